// Round 1
// 411.492 us; speedup vs baseline: 1.3471x; 1.3471x over previous
//
#include <hip/hip_runtime.h>
#include <hip/hip_bf16.h>
#include <cstdint>
#include <cstddef>

// MultiHeadAttention: B=4,S=2048,D=1024,H=16,DK=64, causal. fp32 in, fp32 out.
// Round 8: flash rework —
//   (1) causal pairing: block handles q-tiles {x, 15-x} -> uniform 34 iters/block
//   (2) XOR-swizzled K/V LDS (pre-swizzled global src + swizzled read; rule #21)
//   (3) double-buffered K/V staging, prefetch-before-compute, 1 barrier/iter
//   (4) SM_SCALE folded into Q projection; causal mask only on diagonal tiles
//   (5) s_setprio(1) around MFMA clusters (T5)
// gemm128 = m97-ladder structure (unchanged except epilogue scale arg).
// Fragment layouts (HW-verified): A/B 16x16x32 [m|n=lane&15][k=quad*8+j];
// C/D col=lane&15, row=quad*4+reg.   (validated in rounds 3-7)

namespace {

constexpr int B  = 4;
constexpr int S  = 2048;
constexpr int D  = 1024;
constexpr int H  = 16;
constexpr int DK = 64;
constexpr int M  = B * S;
constexpr float SM_SCALE = 0.125f;
constexpr float NEG_BIG  = -1e30f;

using bf16 = __hip_bfloat16;

typedef __attribute__((ext_vector_type(8))) __bf16 bf16x8;
typedef __attribute__((ext_vector_type(4))) float  f32x4;

__device__ __forceinline__ uint16_t f2bfu(float x) { // RNE fp32->bf16 bits
  uint32_t a = __builtin_bit_cast(uint32_t, x);
  return (uint16_t)((a + 0x7FFFu + ((a >> 16) & 1u)) >> 16);
}
__device__ __forceinline__ uint32_t pk2(float x, float y) {
  return (uint32_t)f2bfu(x) | ((uint32_t)f2bfu(y) << 16);
}

// async 16B global -> LDS (wave-uniform LDS base + lane*16 implicit)
__device__ __forceinline__ void ldst16(const uint4* g, uint4* l) {
  __builtin_amdgcn_global_load_lds(
      (const __attribute__((address_space(1))) void*)g,
      (__attribute__((address_space(3))) void*)l, 16, 0, 0);
}

// ---------------------------------------------------------------------------
// fp32 -> bf16 bulk convert (memory-bound). n8 = elems/8.
// ---------------------------------------------------------------------------
__global__ __launch_bounds__(256)
void cvt_f2b(const float* __restrict__ src, bf16* __restrict__ dst, int n8)
{
  const int i = blockIdx.x * 256 + threadIdx.x;
  if (i >= n8) return;
  const float4 a = ((const float4*)src)[2 * i];
  const float4 b = ((const float4*)src)[2 * i + 1];
  uint4 r;
  r.x = pk2(a.x, a.y); r.y = pk2(a.z, a.w);
  r.z = pk2(b.x, b.y); r.w = pk2(b.z, b.w);
  ((uint4*)dst)[i] = r;
}

// ---------------------------------------------------------------------------
// gemm128: out = (A[M,K](bf16) @ Wb[N,K](bf16)^T + bias(fp32)) * scale.
// 128x128 tile, BK=64, 256 thr = 4 waves (2x2), each wave 64x64 = 4x4 MFMA.
// Staging via global_load_lds width=16, linear LDS (m97 structure).
// MODE 0: fp32 [M,N] store  MODE 1: bf16 [B,H,S,DK]  MODE 2: bf16 [B,H,DK,S]
// ---------------------------------------------------------------------------
template <int MODE>
__global__ __launch_bounds__(256)
void gemm128(const bf16* __restrict__ A, const bf16* __restrict__ Wb,
             const float* __restrict__ bias, void* __restrict__ out,
             int N, int K, float scale)
{
  __shared__ uint4 AsU[1024]; // 128 rows x 8 chunks (16KB)
  __shared__ uint4 BsU[1024];

  const int tid  = threadIdx.x;
  const int w    = tid >> 6;
  const int lane = tid & 63;
  const int lm   = lane & 15;
  const int quad = lane >> 4;
  const int wm   = (w >> 1) * 64;
  const int wn   = (w & 1) * 64;

  const int row0 = blockIdx.y * 128, col0 = blockIdx.x * 128;
  const int g8 = K >> 3; // uint4 per row

  const uint4* Ag = (const uint4*)A + (size_t)row0 * g8;
  const uint4* Bg = (const uint4*)Wb + (size_t)col0 * g8;

  f32x4 acc[4][4] = {};

  for (int kt = 0; kt < K / 64; ++kt) {
    __syncthreads();
#pragma unroll
    for (int i = 0; i < 4; ++i) {
      const int chunk = i * 256 + w * 64 + lane; // 0..1023
      const int r = chunk >> 3, c = chunk & 7;
      ldst16(&Ag[(size_t)r * g8 + kt * 8 + c], &AsU[i * 256 + w * 64]);
      ldst16(&Bg[(size_t)r * g8 + kt * 8 + c], &BsU[i * 256 + w * 64]);
    }
    __syncthreads();
#pragma unroll
    for (int kk = 0; kk < 2; ++kk) {
      bf16x8 af[4], bfr[4];
#pragma unroll
      for (int tm = 0; tm < 4; ++tm)
        af[tm] = __builtin_bit_cast(bf16x8, AsU[(wm + tm * 16 + lm) * 8 + kk * 4 + quad]);
#pragma unroll
      for (int tn = 0; tn < 4; ++tn)
        bfr[tn] = __builtin_bit_cast(bf16x8, BsU[(wn + tn * 16 + lm) * 8 + kk * 4 + quad]);
#pragma unroll
      for (int tm = 0; tm < 4; ++tm)
#pragma unroll
        for (int tn = 0; tn < 4; ++tn)
          acc[tm][tn] = __builtin_amdgcn_mfma_f32_16x16x32_bf16(af[tm], bfr[tn], acc[tm][tn], 0, 0, 0);
    }
  }

#pragma unroll
  for (int tm = 0; tm < 4; ++tm) {
#pragma unroll
    for (int tn = 0; tn < 4; ++tn) {
      const int col = col0 + wn + tn * 16 + lm;
      const float bv = bias[col];
      if (MODE == 2) {
        float vv[4];
#pragma unroll
        for (int r = 0; r < 4; ++r) vv[r] = (acc[tm][tn][r] + bv) * scale;
        const int s0 = row0 + wm + tm * 16 + quad * 4;
        const int b_ = s0 >> 11, ss = s0 & (S - 1);
        const int h_ = col >> 6, dk = col & (DK - 1);
        uint2 st; st.x = pk2(vv[0], vv[1]); st.y = pk2(vv[2], vv[3]);
        *(uint2*)((bf16*)out + (((size_t)b_ * H + h_) * DK + dk) * S + ss) = st;
      } else {
#pragma unroll
        for (int r = 0; r < 4; ++r) {
          const int row = row0 + wm + tm * 16 + quad * 4 + r;
          const float v = (acc[tm][tn][r] + bv) * scale;
          if (MODE == 0) {
            ((float*)out)[(size_t)row * N + col] = v;
          } else {
            const int b_ = row >> 11, s_ = row & (S - 1);
            const int h_ = col >> 6,  dk = col & (DK - 1);
            ((bf16*)out)[(((size_t)b_ * H + h_) * S + s_) * DK + dk] =
                __builtin_bit_cast(bf16, f2bfu(v));
          }
        }
      }
    }
  }
}

// ---------------------------------------------------------------------------
// flash v3 (causal MFMA). Q,K: [B*H,S,DK] bf16 (Q pre-scaled by 1/8);
// Vt: [B*H,DK,S] bf16.
// Grid (B*H, 8): blockIdx.x = bh (fast dim -> same-XCD L2 locality per bh),
// blockIdx.y = pair id; block processes q-tiles {pair, 15-pair} sequentially
// -> uniform 34 key-tile iterations per block.
// Per pass: double-buffered K/V in LDS (XOR-swizzled), prefetch issued right
// after the single per-iteration barrier, compute underneath.
// ---------------------------------------------------------------------------
__global__ __launch_bounds__(256)
void flash_mfma(const bf16* __restrict__ Q, const bf16* __restrict__ K,
                const bf16* __restrict__ Vt, bf16* __restrict__ ctx)
{
  __shared__ uint4 KsU[2][512];          // 2 x (64 keys x 64 dk) (16KB)
  __shared__ uint4 VtU[2][512];          // 2 x (64 d x 64 keys)  (16KB)
  __shared__ uint16_t PsAll[128 * 72];   // P / final O, stride 72 u16 (18KB)

  const int tid  = threadIdx.x;
  const int w    = tid >> 6;
  const int lane = tid & 63;
  const int lm   = lane & 15;
  const int quad = lane >> 4;
  const int bh   = blockIdx.x;           // 0..63
  const int pr   = blockIdx.y;           // 0..7
  const size_t base = (size_t)bh * S * DK;

  const uint4* Kg0 = (const uint4*)(K + base);
  const uint4* Vg0 = (const uint4*)(Vt + (size_t)bh * DK * S);

  // XOR-swizzle (involution). Stage side: LDS[i] <- global(r=i>>3, c=(i&7)^(r&7))
  // via linear global_load_lds dest + permuted per-lane source.
  const int rr   = w * 8 + (lane >> 3);          // source row within 32-row half
  const int csw  = (lane & 7) ^ (lane >> 3);     // pre-swizzled source chunk
  const int swz0 = quad ^ (lm & 7);              // read chunk, kf=0 (row&7==lm&7)
  // kf=1 chunk = swz0 ^ 4

  const int b_ = bh >> 4, h_ = bh & (H - 1);

  for (int pass = 0; pass < 2; ++pass) {
    const int qi = pass ? (15 - pr) : pr;
    const int q0 = qi * 128;

    // Q A-fragments for both row groups
    bf16x8 qf[2][2];
#pragma unroll
    for (int g = 0; g < 2; ++g) {
      const bf16* qrow = Q + base + (size_t)(q0 + g * 64 + w * 16 + lm) * DK;
      qf[g][0] = __builtin_bit_cast(bf16x8, *(const uint4*)(qrow + quad * 8));
      qf[g][1] = __builtin_bit_cast(bf16x8, *(const uint4*)(qrow + 32 + quad * 8));
    }

    f32x4 o[2][4] = {};
    float m_i[2][4], l_i[2][4];
#pragma unroll
    for (int g = 0; g < 2; ++g)
#pragma unroll
      for (int r = 0; r < 4; ++r) { m_i[g][r] = NEG_BIG; l_i[g][r] = 0.f; }

    const int nt = 2 * qi + 2;

    // prologue: stage tile 0 into buf 0 (KsU read-safety vs previous pass is
    // guaranteed by the previous epilogue's __syncthreads)
    ldst16(&Kg0[(size_t)rr * 8 + csw],            &KsU[0][w * 64]);
    ldst16(&Kg0[(size_t)(32 + rr) * 8 + csw],     &KsU[0][256 + w * 64]);
    ldst16(&Vg0[(size_t)rr * (S / 8) + csw],      &VtU[0][w * 64]);
    ldst16(&Vg0[(size_t)(32 + rr) * (S / 8) + csw], &VtU[0][256 + w * 64]);

    int cur = 0;
    for (int t = 0; t < nt; ++t) {
      // single barrier/iter: drains own staged loads (vmcnt(0)) -> buf[cur]
      // ready; also fences prev iteration's reads of buf[cur^1] before the
      // prefetch below overwrites it.
      __syncthreads();
      if (t + 1 < nt) {
        const int k1 = (t + 1) * 64;
        const uint4* kg = Kg0 + (size_t)k1 * 8;
        const uint4* vg = Vg0 + k1 / 8;
        ldst16(&kg[(size_t)rr * 8 + csw],            &KsU[cur ^ 1][w * 64]);
        ldst16(&kg[(size_t)(32 + rr) * 8 + csw],     &KsU[cur ^ 1][256 + w * 64]);
        ldst16(&vg[(size_t)rr * (S / 8) + csw],      &VtU[cur ^ 1][w * 64]);
        ldst16(&vg[(size_t)(32 + rr) * (S / 8) + csw], &VtU[cur ^ 1][256 + w * 64]);
      }
      const int k0 = t * 64;
      const uint4* Ks = KsU[cur];
      const uint4* Vs = VtU[cur];

#pragma unroll
      for (int g = 0; g < 2; ++g) {
        const int qbase = q0 + g * 64 + w * 16;
        if (k0 > qbase + 15) continue;     // wave-uniform causal skip
        uint16_t* Pw = PsAll + (g * 64 + w * 16) * 72;

        // QK^T (scores pre-scaled: Q carries the 1/8)
        f32x4 sc[4];
        __builtin_amdgcn_s_setprio(1);
#pragma unroll
        for (int tn = 0; tn < 4; ++tn) {
          sc[tn] = f32x4{0.f, 0.f, 0.f, 0.f};
          const int row = tn * 16 + lm;
          bf16x8 kb0 = __builtin_bit_cast(bf16x8, Ks[row * 8 + swz0]);
          bf16x8 kb1 = __builtin_bit_cast(bf16x8, Ks[row * 8 + (swz0 ^ 4)]);
          sc[tn] = __builtin_amdgcn_mfma_f32_16x16x32_bf16(qf[g][0], kb0, sc[tn], 0, 0, 0);
          sc[tn] = __builtin_amdgcn_mfma_f32_16x16x32_bf16(qf[g][1], kb1, sc[tn], 0, 0, 0);
        }
        __builtin_amdgcn_s_setprio(0);

        // causal mask — diagonal tiles only (wave-uniform test)
        if (k0 + 63 > qbase) {
          const int qg = qbase + quad * 4;
#pragma unroll
          for (int tn = 0; tn < 4; ++tn) {
            const int kg_ = k0 + tn * 16 + lm;
#pragma unroll
            for (int r = 0; r < 4; ++r)
              if (kg_ > qg + r) sc[tn][r] = NEG_BIG;
          }
        }

        // online softmax: max reduced now, row-sum kept lane-partial
#pragma unroll
        for (int r = 0; r < 4; ++r) {
          float mr = fmaxf(fmaxf(sc[0][r], sc[1][r]), fmaxf(sc[2][r], sc[3][r]));
#pragma unroll
          for (int off = 8; off; off >>= 1) mr = fmaxf(mr, __shfl_xor(mr, off));
          const float mn = fmaxf(m_i[g][r], mr);
          const float al = __expf(m_i[g][r] - mn);
          float ls = 0.f;
#pragma unroll
          for (int tn = 0; tn < 4; ++tn) {
            const float p = __expf(sc[tn][r] - mn);
            ls += p;
            Pw[(quad * 4 + r) * 72 + tn * 16 + lm] = f2bfu(p);
          }
          l_i[g][r] = l_i[g][r] * al + ls;
          m_i[g][r] = mn;
#pragma unroll
          for (int tn = 0; tn < 4; ++tn) o[g][tn][r] *= al;
        }

        // P -> A-frags (own wave's LDS slice), PV
        bf16x8 ap0, ap1;
        {
          const uint16_t* prp = Pw + lm * 72 + quad * 8;
          ap0 = __builtin_bit_cast(bf16x8, *(const uint4*)prp);
          ap1 = __builtin_bit_cast(bf16x8, *(const uint4*)(prp + 32));
        }
        __builtin_amdgcn_s_setprio(1);
#pragma unroll
        for (int tn = 0; tn < 4; ++tn) {
          const int row = tn * 16 + lm;      // d index
          bf16x8 vb0 = __builtin_bit_cast(bf16x8, Vs[row * 8 + swz0]);
          bf16x8 vb1 = __builtin_bit_cast(bf16x8, Vs[row * 8 + (swz0 ^ 4)]);
          o[g][tn] = __builtin_amdgcn_mfma_f32_16x16x32_bf16(ap0, vb0, o[g][tn], 0, 0, 0);
          o[g][tn] = __builtin_amdgcn_mfma_f32_16x16x32_bf16(ap1, vb1, o[g][tn], 0, 0, 0);
        }
        __builtin_amdgcn_s_setprio(0);
      }
      cur ^= 1;
    }

    // epilogue: reduce l, normalize, stash O in PsAll, coalesced store.
    // First barrier also fences last compute before next pass's prologue STAGE.
    __syncthreads();
#pragma unroll
    for (int g = 0; g < 2; ++g) {
      uint16_t* Pw = PsAll + (g * 64 + w * 16) * 72;
#pragma unroll
      for (int r = 0; r < 4; ++r) {
        float lr = l_i[g][r];
#pragma unroll
        for (int off = 8; off; off >>= 1) lr += __shfl_xor(lr, off);
        const float inv = 1.f / lr;
#pragma unroll
        for (int tn = 0; tn < 4; ++tn)
          Pw[(quad * 4 + r) * 72 + tn * 16 + lm] = f2bfu(o[g][tn][r] * inv);
      }
    }
    __syncthreads();

#pragma unroll
    for (int i = 0; i < 4; ++i) {
      const int idx = tid + i * 256;         // 0..1023 uint4
      const int row = idx >> 3, c = idx & 7;
      const uint4 v = *(const uint4*)(PsAll + row * 72 + c * 8);
      *(uint4*)(ctx + ((((size_t)b_ * S + q0 + row) * H + h_) << 6) + c * 8) = v;
    }
  }
}

} // namespace

extern "C" void kernel_launch(void* const* d_in, const int* in_sizes, int n_in,
                              void* d_out, int out_size, void* d_ws, size_t ws_size,
                              hipStream_t stream)
{
  const float* query = (const float*)d_in[0];
  const float* key_  = (const float*)d_in[1];
  const float* value = (const float*)d_in[2];
  const float* Wq    = (const float*)d_in[3];
  const float* bq    = (const float*)d_in[4];
  const float* Wk    = (const float*)d_in[5];
  const float* bk    = (const float*)d_in[6];
  const float* Wv    = (const float*)d_in[7];
  const float* bv    = (const float*)d_in[8];
  const float* Wo    = (const float*)d_in[9];
  const float* bo    = (const float*)d_in[10];
  // d_in[11]: causal mask — applied analytically in flash_mfma.

  const size_t qkv = (size_t)B * H * S * DK; // 8,388,608 elems
  bf16* slot0 = (bf16*)d_ws;        // q_ws; later Wo_bf
  bf16* slot1 = slot0 + qkv;        // k_ws
  bf16* slot2 = slot1 + qkv;        // vt_ws [B,H,DK,S]
  bf16* slot3 = slot2 + qkv;        // weight scratch, then ctx [B,S,D]
  bf16* inbf  = (bf16*)d_out;       // 16.8MB input-conversion scratch
                                    // (d_out fully rewritten by final GEMM)

  const int n8in = (int)(qkv / 8);          // 1048576
  const int n8w  = (D * D) / 8;             // 131072
  const dim3 cvtIn(n8in / 256), cvtW(n8w / 256);
  const dim3 gproj(D / 128, M / 128);       // (8, 64)
  const dim3 gattn(B * H, 8);               // (64, 8) — bh fast => per-bh XCD locality

  // Q (scores pre-scale folded in: q = (x@Wq^T + bq) * 1/8)
  cvt_f2b<<<cvtIn, 256, 0, stream>>>(query, inbf, n8in);
  cvt_f2b<<<cvtW,  256, 0, stream>>>(Wq, slot3, n8w);
  gemm128<1><<<gproj, 256, 0, stream>>>(inbf, slot3, bq, slot0, D, D, SM_SCALE);
  // K
  cvt_f2b<<<cvtIn, 256, 0, stream>>>(key_, inbf, n8in);
  cvt_f2b<<<cvtW,  256, 0, stream>>>(Wk, slot3, n8w);
  gemm128<1><<<gproj, 256, 0, stream>>>(inbf, slot3, bk, slot1, D, D, 1.0f);
  // V (transposed output)
  cvt_f2b<<<cvtIn, 256, 0, stream>>>(value, inbf, n8in);
  cvt_f2b<<<cvtW,  256, 0, stream>>>(Wv, slot3, n8w);
  gemm128<2><<<gproj, 256, 0, stream>>>(inbf, slot3, bv, slot2, D, D, 1.0f);
  // attention -> ctx (overwrites weight scratch in slot3)
  flash_mfma<<<gattn, 256, 0, stream>>>(slot0, slot1, slot2, slot3);
  // output projection (fp32 store); Wo_bf stashed in dead slot0
  cvt_f2b<<<cvtW, 256, 0, stream>>>(Wo, slot0, n8w);
  gemm128<0><<<gproj, 256, 0, stream>>>(slot3, slot0, bo, d_out, D, D, 1.0f);
}

// Round 2
// 384.096 us; speedup vs baseline: 1.4432x; 1.0713x over previous
//
#include <hip/hip_runtime.h>
#include <hip/hip_bf16.h>
#include <cstdint>
#include <cstddef>

// MultiHeadAttention: B=4,S=2048,D=1024,H=16,DK=64, causal. fp32 in, fp32 out.
// Round 9:
//   flash: 8-wave (512-thr) blocks, same (64,8) grid -> 16 waves/CU (was 8);
//          exp2-domain softmax (log2e folded into Q projection scale);
//          T13 defer-rescale (THR=8 log2 => P<=256, bf16-safe).
//   gemm128: double-buffered LDS + prefetch-before-compute (T3-min);
//          grid-capped at 2 blocks/CU so 64KB LDS costs no occupancy.
// Carried from R8 (verified): causal pairing {x,15-x}; XOR-swizzled K/V LDS
// (pre-swizzled global src + swizzled read, rule #21); setprio around MFMA.
// Fragment layouts (HW-verified): A/B 16x16x32 [m|n=lane&15][k=quad*8+j];
// C/D col=lane&15, row=quad*4+reg.

namespace {

constexpr int B  = 4;
constexpr int S  = 2048;
constexpr int D  = 1024;
constexpr int H  = 16;
constexpr int DK = 64;
constexpr int M  = B * S;
constexpr float LOG2E    = 1.44269504088896f;
constexpr float QSCALE   = 0.125f * LOG2E;   // sm-scale folded with log2(e)
constexpr float NEG_BIG  = -1e30f;
constexpr float DEFER_THR = 8.0f;            // T13, log2 domain (p <= 2^8)

using bf16 = __hip_bfloat16;

typedef __attribute__((ext_vector_type(8))) __bf16 bf16x8;
typedef __attribute__((ext_vector_type(4))) float  f32x4;

__device__ __forceinline__ uint16_t f2bfu(float x) { // RNE fp32->bf16 bits
  uint32_t a = __builtin_bit_cast(uint32_t, x);
  return (uint16_t)((a + 0x7FFFu + ((a >> 16) & 1u)) >> 16);
}
__device__ __forceinline__ uint32_t pk2(float x, float y) {
  return (uint32_t)f2bfu(x) | ((uint32_t)f2bfu(y) << 16);
}
__device__ __forceinline__ float ex2(float x) { // 2^x, same class as __expf's core
  float r; asm("v_exp_f32 %0, %1" : "=v"(r) : "v"(x)); return r;
}

// async 16B global -> LDS (wave-uniform LDS base + lane*16 implicit)
__device__ __forceinline__ void ldst16(const uint4* g, uint4* l) {
  __builtin_amdgcn_global_load_lds(
      (const __attribute__((address_space(1))) void*)g,
      (__attribute__((address_space(3))) void*)l, 16, 0, 0);
}

// ---------------------------------------------------------------------------
// fp32 -> bf16 bulk convert (memory-bound). n8 = elems/8.
// ---------------------------------------------------------------------------
__global__ __launch_bounds__(256)
void cvt_f2b(const float* __restrict__ src, bf16* __restrict__ dst, int n8)
{
  const int i = blockIdx.x * 256 + threadIdx.x;
  if (i >= n8) return;
  const float4 a = ((const float4*)src)[2 * i];
  const float4 b = ((const float4*)src)[2 * i + 1];
  uint4 r;
  r.x = pk2(a.x, a.y); r.y = pk2(a.z, a.w);
  r.z = pk2(b.x, b.y); r.w = pk2(b.z, b.w);
  ((uint4*)dst)[i] = r;
}

// ---------------------------------------------------------------------------
// gemm128: out = (A[M,K](bf16) @ Wb[N,K](bf16)^T + bias(fp32)) * scale.
// 128x128 tile, BK=64, 256 thr = 4 waves (2x2), each wave 64x64 = 4x4 MFMA.
// Double-buffered LDS; prefetch kt+1 issued right after the single barrier,
// compute of kt underneath (stage latency hidden under 32 MFMA).
// MODE 0: fp32 [M,N] store  MODE 1: bf16 [B,H,S,DK]  MODE 2: bf16 [B,H,DK,S]
// ---------------------------------------------------------------------------
template <int MODE>
__global__ __launch_bounds__(256)
void gemm128(const bf16* __restrict__ A, const bf16* __restrict__ Wb,
             const float* __restrict__ bias, void* __restrict__ out,
             int N, int K, float scale)
{
  __shared__ uint4 AsU[2][1024]; // 2 x 128 rows x 8 chunks (32KB)
  __shared__ uint4 BsU[2][1024];

  const int tid  = threadIdx.x;
  const int w    = tid >> 6;
  const int lane = tid & 63;
  const int lm   = lane & 15;
  const int quad = lane >> 4;
  const int wm   = (w >> 1) * 64;
  const int wn   = (w & 1) * 64;

  const int row0 = blockIdx.y * 128, col0 = blockIdx.x * 128;
  const int g8 = K >> 3; // uint4 per row

  const uint4* Ag = (const uint4*)A + (size_t)row0 * g8;
  const uint4* Bg = (const uint4*)Wb + (size_t)col0 * g8;

  f32x4 acc[4][4] = {};
  const int KT = K / 64;

  // prologue: stage kt=0 into buf 0
#pragma unroll
  for (int i = 0; i < 4; ++i) {
    const int chunk = i * 256 + w * 64 + lane; // 0..1023
    const int r = chunk >> 3, c = chunk & 7;
    ldst16(&Ag[(size_t)r * g8 + c], &AsU[0][i * 256 + w * 64]);
    ldst16(&Bg[(size_t)r * g8 + c], &BsU[0][i * 256 + w * 64]);
  }

  int cur = 0;
  for (int kt = 0; kt < KT; ++kt) {
    // single barrier/iter: drains own staged loads (buf[cur] ready) and
    // fences prev iteration's reads of buf[cur^1] before we overwrite it.
    __syncthreads();
    if (kt + 1 < KT) {
#pragma unroll
      for (int i = 0; i < 4; ++i) {
        const int chunk = i * 256 + w * 64 + lane;
        const int r = chunk >> 3, c = chunk & 7;
        ldst16(&Ag[(size_t)r * g8 + (kt + 1) * 8 + c], &AsU[cur ^ 1][i * 256 + w * 64]);
        ldst16(&Bg[(size_t)r * g8 + (kt + 1) * 8 + c], &BsU[cur ^ 1][i * 256 + w * 64]);
      }
    }
#pragma unroll
    for (int kk = 0; kk < 2; ++kk) {
      bf16x8 af[4], bfr[4];
#pragma unroll
      for (int tm = 0; tm < 4; ++tm)
        af[tm] = __builtin_bit_cast(bf16x8, AsU[cur][(wm + tm * 16 + lm) * 8 + kk * 4 + quad]);
#pragma unroll
      for (int tn = 0; tn < 4; ++tn)
        bfr[tn] = __builtin_bit_cast(bf16x8, BsU[cur][(wn + tn * 16 + lm) * 8 + kk * 4 + quad]);
#pragma unroll
      for (int tm = 0; tm < 4; ++tm)
#pragma unroll
        for (int tn = 0; tn < 4; ++tn)
          acc[tm][tn] = __builtin_amdgcn_mfma_f32_16x16x32_bf16(af[tm], bfr[tn], acc[tm][tn], 0, 0, 0);
    }
    cur ^= 1;
  }

#pragma unroll
  for (int tm = 0; tm < 4; ++tm) {
#pragma unroll
    for (int tn = 0; tn < 4; ++tn) {
      const int col = col0 + wn + tn * 16 + lm;
      const float bv = bias[col];
      if (MODE == 2) {
        float vv[4];
#pragma unroll
        for (int r = 0; r < 4; ++r) vv[r] = (acc[tm][tn][r] + bv) * scale;
        const int s0 = row0 + wm + tm * 16 + quad * 4;
        const int b_ = s0 >> 11, ss = s0 & (S - 1);
        const int h_ = col >> 6, dk = col & (DK - 1);
        uint2 st; st.x = pk2(vv[0], vv[1]); st.y = pk2(vv[2], vv[3]);
        *(uint2*)((bf16*)out + (((size_t)b_ * H + h_) * DK + dk) * S + ss) = st;
      } else {
#pragma unroll
        for (int r = 0; r < 4; ++r) {
          const int row = row0 + wm + tm * 16 + quad * 4 + r;
          const float v = (acc[tm][tn][r] + bv) * scale;
          if (MODE == 0) {
            ((float*)out)[(size_t)row * N + col] = v;
          } else {
            const int b_ = row >> 11, s_ = row & (S - 1);
            const int h_ = col >> 6,  dk = col & (DK - 1);
            ((bf16*)out)[(((size_t)b_ * H + h_) * S + s_) * DK + dk] =
                __builtin_bit_cast(bf16, f2bfu(v));
          }
        }
      }
    }
  }
}

// ---------------------------------------------------------------------------
// flash v4 (causal MFMA). Q,K: [B*H,S,DK] bf16 (Q pre-scaled by 0.125*log2e);
// Vt: [B*H,DK,S] bf16. Softmax in exp2 domain.
// Grid (B*H, 8), 512 threads = 8 waves; q-tile 128 rows, wave w owns rows
// q0 + w*16 + [0,16). Block processes q-tiles {pr, 15-pr} -> uniform 34 iters.
// K/V double-buffered in LDS (XOR-swizzled), prefetch after single barrier.
// ---------------------------------------------------------------------------
__global__ __launch_bounds__(512)
void flash_mfma(const bf16* __restrict__ Q, const bf16* __restrict__ K,
                const bf16* __restrict__ Vt, bf16* __restrict__ ctx)
{
  __shared__ uint4 KsU[2][512];          // 2 x (64 keys x 64 dk) (16KB)
  __shared__ uint4 VtU[2][512];          // 2 x (64 d x 64 keys)  (16KB)
  __shared__ uint16_t PsAll[128 * 72];   // P / final O, stride 72 u16 (18KB)

  const int tid  = threadIdx.x;
  const int w    = tid >> 6;             // 0..7
  const int lane = tid & 63;
  const int lm   = lane & 15;
  const int quad = lane >> 4;
  const int bh   = blockIdx.x;           // 0..63
  const int pr   = blockIdx.y;           // 0..7
  const size_t base = (size_t)bh * S * DK;

  const uint4* Kg0 = (const uint4*)(K + base);
  const uint4* Vg0 = (const uint4*)(Vt + (size_t)bh * DK * S);

  // XOR-swizzle (involution): LDS chunk i holds global (r=i>>3, c=(i&7)^(r&7));
  // staged with linear LDS dest + permuted per-lane global source.
  const int rr   = w * 8 + (lane >> 3);          // source row within tile
  const int csw  = (lane & 7) ^ (lane >> 3);     // pre-swizzled source chunk
  const int swz0 = quad ^ (lm & 7);              // read chunk kf=0; kf=1 -> ^4

  uint16_t* const Pw = PsAll + (w * 16) * 72;    // this wave's 16 P rows
  const int b_ = bh >> 4, h_ = bh & (H - 1);

  for (int pass = 0; pass < 2; ++pass) {
    const int qi = pass ? (15 - pr) : pr;
    const int q0 = qi * 128;
    const int qbase = q0 + w * 16;

    bf16x8 qf0, qf1;
    {
      const bf16* qrow = Q + base + (size_t)(qbase + lm) * DK;
      qf0 = __builtin_bit_cast(bf16x8, *(const uint4*)(qrow + quad * 8));
      qf1 = __builtin_bit_cast(bf16x8, *(const uint4*)(qrow + 32 + quad * 8));
    }

    f32x4 o[4] = {};
    float m_i[4], l_i[4];
#pragma unroll
    for (int r = 0; r < 4; ++r) { m_i[r] = NEG_BIG; l_i[r] = 0.f; }

    const int nt = 2 * qi + 2;

    // prologue: stage tile 0 into buf 0 (read-safety vs previous pass is
    // guaranteed by the epilogue barriers + loop-top barrier)
    ldst16(&Kg0[(size_t)rr * 8 + csw],        &KsU[0][w * 64]);
    ldst16(&Vg0[(size_t)rr * (S / 8) + csw],  &VtU[0][w * 64]);

    int cur = 0;
    for (int t = 0; t < nt; ++t) {
      __syncthreads();
      if (t + 1 < nt) {
        const int k1 = (t + 1) * 64;
        ldst16(&Kg0[(size_t)(k1 + rr) * 8 + csw],         &KsU[cur ^ 1][w * 64]);
        ldst16(&Vg0[(size_t)rr * (S / 8) + k1 / 8 + csw], &VtU[cur ^ 1][w * 64]);
      }
      const int k0 = t * 64;
      if (k0 <= qbase + 15) {              // wave-uniform causal skip
        const uint4* Ks = KsU[cur];
        const uint4* Vs = VtU[cur];

        // QK^T (scores already in exp2 domain: Q carries 0.125*log2e)
        f32x4 sc[4];
        __builtin_amdgcn_s_setprio(1);
#pragma unroll
        for (int tn = 0; tn < 4; ++tn) {
          const int row = tn * 16 + lm;
          bf16x8 kb0 = __builtin_bit_cast(bf16x8, Ks[row * 8 + swz0]);
          bf16x8 kb1 = __builtin_bit_cast(bf16x8, Ks[row * 8 + (swz0 ^ 4)]);
          sc[tn] = __builtin_amdgcn_mfma_f32_16x16x32_bf16(
                       qf0, kb0, f32x4{0.f, 0.f, 0.f, 0.f}, 0, 0, 0);
          sc[tn] = __builtin_amdgcn_mfma_f32_16x16x32_bf16(qf1, kb1, sc[tn], 0, 0, 0);
        }
        __builtin_amdgcn_s_setprio(0);

        // causal mask — diagonal tiles only (wave-uniform test)
        if (k0 + 63 > qbase) {
          const int qg = qbase + quad * 4;
#pragma unroll
          for (int tn = 0; tn < 4; ++tn) {
            const int kg_ = k0 + tn * 16 + lm;
#pragma unroll
            for (int r = 0; r < 4; ++r)
              if (kg_ > qg + r) sc[tn][r] = NEG_BIG;
          }
        }

        // online softmax, T13 defer-rescale (wave-uniform decision)
        float mr[4];
        bool need = false;
#pragma unroll
        for (int r = 0; r < 4; ++r) {
          float m4 = fmaxf(fmaxf(sc[0][r], sc[1][r]), fmaxf(sc[2][r], sc[3][r]));
#pragma unroll
          for (int off = 8; off; off >>= 1) m4 = fmaxf(m4, __shfl_xor(m4, off));
          mr[r] = m4;
          need = need || (m4 > m_i[r] + DEFER_THR);
        }
        if (__any(need)) {
#pragma unroll
          for (int r = 0; r < 4; ++r) {
            const float mn = fmaxf(m_i[r], mr[r]);
            const float al = ex2(m_i[r] - mn);
            l_i[r] *= al;
#pragma unroll
            for (int tn = 0; tn < 4; ++tn) o[tn][r] *= al;
            m_i[r] = mn;
          }
        }
#pragma unroll
        for (int r = 0; r < 4; ++r) {
          float ls = 0.f;
#pragma unroll
          for (int tn = 0; tn < 4; ++tn) {
            const float p = ex2(sc[tn][r] - m_i[r]);   // bounded by 2^THR
            ls += p;
            Pw[(quad * 4 + r) * 72 + tn * 16 + lm] = f2bfu(p);
          }
          l_i[r] += ls;
        }

        // P -> A-frags (own wave's LDS slice), PV
        bf16x8 ap0, ap1;
        {
          const uint16_t* prp = Pw + lm * 72 + quad * 8;
          ap0 = __builtin_bit_cast(bf16x8, *(const uint4*)prp);
          ap1 = __builtin_bit_cast(bf16x8, *(const uint4*)(prp + 32));
        }
        __builtin_amdgcn_s_setprio(1);
#pragma unroll
        for (int tn = 0; tn < 4; ++tn) {
          const int row = tn * 16 + lm;    // d index
          bf16x8 vb0 = __builtin_bit_cast(bf16x8, Vs[row * 8 + swz0]);
          bf16x8 vb1 = __builtin_bit_cast(bf16x8, Vs[row * 8 + (swz0 ^ 4)]);
          o[tn] = __builtin_amdgcn_mfma_f32_16x16x32_bf16(ap0, vb0, o[tn], 0, 0, 0);
          o[tn] = __builtin_amdgcn_mfma_f32_16x16x32_bf16(ap1, vb1, o[tn], 0, 0, 0);
        }
        __builtin_amdgcn_s_setprio(0);
      }
      cur ^= 1;
    }

    // epilogue: reduce l, normalize, stash O in PsAll, coalesced store
    __syncthreads();
#pragma unroll
    for (int r = 0; r < 4; ++r) {
      float lr = l_i[r];
#pragma unroll
      for (int off = 8; off; off >>= 1) lr += __shfl_xor(lr, off);
      const float inv = 1.f / lr;
#pragma unroll
      for (int tn = 0; tn < 4; ++tn)
        Pw[(quad * 4 + r) * 72 + tn * 16 + lm] = f2bfu(o[tn][r] * inv);
    }
    __syncthreads();

#pragma unroll
    for (int i = 0; i < 2; ++i) {
      const int idx = tid + i * 512;       // 0..1023 uint4
      const int row = idx >> 3, c = idx & 7;
      const uint4 v = *(const uint4*)(PsAll + row * 72 + c * 8);
      *(uint4*)(ctx + ((((size_t)b_ * S + q0 + row) * H + h_) << 6) + c * 8) = v;
    }
  }
}

} // namespace

extern "C" void kernel_launch(void* const* d_in, const int* in_sizes, int n_in,
                              void* d_out, int out_size, void* d_ws, size_t ws_size,
                              hipStream_t stream)
{
  const float* query = (const float*)d_in[0];
  const float* key_  = (const float*)d_in[1];
  const float* value = (const float*)d_in[2];
  const float* Wq    = (const float*)d_in[3];
  const float* bq    = (const float*)d_in[4];
  const float* Wk    = (const float*)d_in[5];
  const float* bk    = (const float*)d_in[6];
  const float* Wv    = (const float*)d_in[7];
  const float* bv    = (const float*)d_in[8];
  const float* Wo    = (const float*)d_in[9];
  const float* bo    = (const float*)d_in[10];
  // d_in[11]: causal mask — applied analytically in flash_mfma.

  const size_t qkv = (size_t)B * H * S * DK; // 8,388,608 elems
  bf16* slot0 = (bf16*)d_ws;        // q_ws; later Wo_bf
  bf16* slot1 = slot0 + qkv;        // k_ws
  bf16* slot2 = slot1 + qkv;        // vt_ws [B,H,DK,S]
  bf16* slot3 = slot2 + qkv;        // weight scratch, then ctx [B,S,D]
  bf16* inbf  = (bf16*)d_out;       // 16.8MB input-conversion scratch
                                    // (d_out fully rewritten by final GEMM)

  const int n8in = (int)(qkv / 8);          // 1048576
  const int n8w  = (D * D) / 8;             // 131072
  const dim3 cvtIn(n8in / 256), cvtW(n8w / 256);
  const dim3 gproj(D / 128, M / 128);       // (8, 64)
  const dim3 gattn(B * H, 8);               // (64, 8) — bh fast => per-bh L2 locality

  // Q (exp2-domain fold: q = (x@Wq^T + bq) * 0.125 * log2e)
  cvt_f2b<<<cvtIn, 256, 0, stream>>>(query, inbf, n8in);
  cvt_f2b<<<cvtW,  256, 0, stream>>>(Wq, slot3, n8w);
  gemm128<1><<<gproj, 256, 0, stream>>>(inbf, slot3, bq, slot0, D, D, QSCALE);
  // K
  cvt_f2b<<<cvtIn, 256, 0, stream>>>(key_, inbf, n8in);
  cvt_f2b<<<cvtW,  256, 0, stream>>>(Wk, slot3, n8w);
  gemm128<1><<<gproj, 256, 0, stream>>>(inbf, slot3, bk, slot1, D, D, 1.0f);
  // V (transposed output)
  cvt_f2b<<<cvtIn, 256, 0, stream>>>(value, inbf, n8in);
  cvt_f2b<<<cvtW,  256, 0, stream>>>(Wv, slot3, n8w);
  gemm128<2><<<gproj, 256, 0, stream>>>(inbf, slot3, bv, slot2, D, D, 1.0f);
  // attention -> ctx (overwrites weight scratch in slot3)
  flash_mfma<<<gattn, 512, 0, stream>>>(slot0, slot1, slot2, slot3);
  // output projection (fp32 store); Wo_bf stashed in dead slot0
  cvt_f2b<<<cvtW, 256, 0, stream>>>(Wo, slot0, n8w);
  gemm128<0><<<gproj, 256, 0, stream>>>(slot3, slot0, bo, d_out, D, D, 1.0f);
}

// Round 3
// 343.418 us; speedup vs baseline: 1.6141x; 1.1185x over previous
//
#include <hip/hip_runtime.h>
#include <hip/hip_bf16.h>
#include <cstdint>
#include <cstddef>

// MultiHeadAttention: B=4,S=2048,D=1024,H=16,DK=64, causal. fp32 in, fp32 out.
// Round 10:
//   flash: T12-style in-register softmax with ZERO cross-lane P movement:
//     - swapped QK^T (mfma(K,Q) -> S^T): lane's col = its q-row
//     - key-permuted K feed (kappa = 32(tn>>1)+8q+4(tn&1)+r) so each lane's
//       16 scores ARE its PV A-frag keys -> P packed via 8 v_cvt_pk_bf16_f32,
//       no LDS round-trip, no bpermute; V LDS layout stays linear
//     - swizzle extended with row-bit-3: f(row)=(row&7)^((row>>3&1)<<2) so
//       both the permuted K reads and linear V reads stay <=8 lanes/column
//     - row max/sum per-lane + 2 shfl_xor (was 16 shfl + 16 ds_write_b16)
//   launches: 12 -> 9 (merged input cvt x3, merged Wq/Wk cvt)
// Carried (verified): causal pairing {x,15-x}; dbuf K/V staging; exp2-domain
// softmax w/ QSCALE fold; T13 defer-rescale; setprio; gemm128 m97+dbuf.
// Fragment layouts (HW-verified): A/B 16x16x32 [m|n=lane&15][k=quad*8+j];
// C/D col=lane&15, row=quad*4+reg.

namespace {

constexpr int B  = 4;
constexpr int S  = 2048;
constexpr int D  = 1024;
constexpr int H  = 16;
constexpr int DK = 64;
constexpr int M  = B * S;
constexpr float LOG2E     = 1.44269504088896f;
constexpr float QSCALE    = 0.125f * LOG2E;  // sm-scale folded with log2(e)
constexpr float NEG_BIG   = -1e30f;
constexpr float DEFER_THR = 8.0f;            // T13, log2 domain (p <= 2^8)

using bf16 = __hip_bfloat16;

typedef __attribute__((ext_vector_type(8))) __bf16 bf16x8;
typedef __attribute__((ext_vector_type(4))) float  f32x4;

__device__ __forceinline__ uint16_t f2bfu(float x) { // RNE fp32->bf16 bits
  uint32_t a = __builtin_bit_cast(uint32_t, x);
  return (uint16_t)((a + 0x7FFFu + ((a >> 16) & 1u)) >> 16);
}
__device__ __forceinline__ uint32_t pk2(float x, float y) {
  return (uint32_t)f2bfu(x) | ((uint32_t)f2bfu(y) << 16);
}
__device__ __forceinline__ float ex2(float x) { // 2^x
  float r; asm("v_exp_f32 %0, %1" : "=v"(r) : "v"(x)); return r;
}
__device__ __forceinline__ uint32_t cvtpk(float lo, float hi) { // {bf16(lo),bf16(hi)}
  uint32_t r;
  asm("v_cvt_pk_bf16_f32 %0, %1, %2" : "=v"(r) : "v"(lo), "v"(hi));
  return r;
}
__device__ __forceinline__ float hmax4(f32x4 v) {
  return fmaxf(fmaxf(v[0], v[1]), fmaxf(v[2], v[3]));
}

// async 16B global -> LDS (wave-uniform LDS base + lane*16 implicit)
__device__ __forceinline__ void ldst16(const uint4* g, uint4* l) {
  __builtin_amdgcn_global_load_lds(
      (const __attribute__((address_space(1))) void*)g,
      (__attribute__((address_space(3))) void*)l, 16, 0, 0);
}

// ---------------------------------------------------------------------------
// fp32 -> bf16 bulk convert, up to 3 tensors per launch (z selects). n8=elems/8.
// ---------------------------------------------------------------------------
__global__ __launch_bounds__(256)
void cvt3(const float* __restrict__ a, const float* __restrict__ b,
          const float* __restrict__ c, bf16* __restrict__ x,
          bf16* __restrict__ y, bf16* __restrict__ z_, int n8)
{
  const int zz = blockIdx.y;
  const float* src = (zz == 0) ? a : (zz == 1) ? b : c;
  bf16*        dst = (zz == 0) ? x : (zz == 1) ? y : z_;
  const int i = blockIdx.x * 256 + threadIdx.x;
  if (i >= n8) return;
  const float4 p = ((const float4*)src)[2 * i];
  const float4 q = ((const float4*)src)[2 * i + 1];
  uint4 r;
  r.x = pk2(p.x, p.y); r.y = pk2(p.z, p.w);
  r.z = pk2(q.x, q.y); r.w = pk2(q.z, q.w);
  ((uint4*)dst)[i] = r;
}

// ---------------------------------------------------------------------------
// gemm128: out = (A[M,K](bf16) @ Wb[N,K](bf16)^T + bias(fp32)) * scale.
// 128x128 tile, BK=64, 256 thr = 4 waves (2x2), each wave 64x64 = 4x4 MFMA.
// Double-buffered LDS; prefetch kt+1 after the single per-iter barrier.
// MODE 0: fp32 [M,N] store  MODE 1: bf16 [B,H,S,DK]  MODE 2: bf16 [B,H,DK,S]
// ---------------------------------------------------------------------------
template <int MODE>
__global__ __launch_bounds__(256)
void gemm128(const bf16* __restrict__ A, const bf16* __restrict__ Wb,
             const float* __restrict__ bias, void* __restrict__ out,
             int N, int K, float scale)
{
  __shared__ uint4 AsU[2][1024]; // 2 x 128 rows x 8 chunks (32KB)
  __shared__ uint4 BsU[2][1024];

  const int tid  = threadIdx.x;
  const int w    = tid >> 6;
  const int lane = tid & 63;
  const int lm   = lane & 15;
  const int quad = lane >> 4;
  const int wm   = (w >> 1) * 64;
  const int wn   = (w & 1) * 64;

  const int row0 = blockIdx.y * 128, col0 = blockIdx.x * 128;
  const int g8 = K >> 3; // uint4 per row

  const uint4* Ag = (const uint4*)A + (size_t)row0 * g8;
  const uint4* Bg = (const uint4*)Wb + (size_t)col0 * g8;

  f32x4 acc[4][4] = {};
  const int KT = K / 64;

  // prologue: stage kt=0 into buf 0
#pragma unroll
  for (int i = 0; i < 4; ++i) {
    const int chunk = i * 256 + w * 64 + lane; // 0..1023
    const int r = chunk >> 3, c = chunk & 7;
    ldst16(&Ag[(size_t)r * g8 + c], &AsU[0][i * 256 + w * 64]);
    ldst16(&Bg[(size_t)r * g8 + c], &BsU[0][i * 256 + w * 64]);
  }

  int cur = 0;
  for (int kt = 0; kt < KT; ++kt) {
    __syncthreads();
    if (kt + 1 < KT) {
#pragma unroll
      for (int i = 0; i < 4; ++i) {
        const int chunk = i * 256 + w * 64 + lane;
        const int r = chunk >> 3, c = chunk & 7;
        ldst16(&Ag[(size_t)r * g8 + (kt + 1) * 8 + c], &AsU[cur ^ 1][i * 256 + w * 64]);
        ldst16(&Bg[(size_t)r * g8 + (kt + 1) * 8 + c], &BsU[cur ^ 1][i * 256 + w * 64]);
      }
    }
#pragma unroll
    for (int kk = 0; kk < 2; ++kk) {
      bf16x8 af[4], bfr[4];
#pragma unroll
      for (int tm = 0; tm < 4; ++tm)
        af[tm] = __builtin_bit_cast(bf16x8, AsU[cur][(wm + tm * 16 + lm) * 8 + kk * 4 + quad]);
#pragma unroll
      for (int tn = 0; tn < 4; ++tn)
        bfr[tn] = __builtin_bit_cast(bf16x8, BsU[cur][(wn + tn * 16 + lm) * 8 + kk * 4 + quad]);
#pragma unroll
      for (int tm = 0; tm < 4; ++tm)
#pragma unroll
        for (int tn = 0; tn < 4; ++tn)
          acc[tm][tn] = __builtin_amdgcn_mfma_f32_16x16x32_bf16(af[tm], bfr[tn], acc[tm][tn], 0, 0, 0);
    }
    cur ^= 1;
  }

#pragma unroll
  for (int tm = 0; tm < 4; ++tm) {
#pragma unroll
    for (int tn = 0; tn < 4; ++tn) {
      const int col = col0 + wn + tn * 16 + lm;
      const float bv = bias[col];
      if (MODE == 2) {
        float vv[4];
#pragma unroll
        for (int r = 0; r < 4; ++r) vv[r] = (acc[tm][tn][r] + bv) * scale;
        const int s0 = row0 + wm + tm * 16 + quad * 4;
        const int b_ = s0 >> 11, ss = s0 & (S - 1);
        const int h_ = col >> 6, dk = col & (DK - 1);
        uint2 st; st.x = pk2(vv[0], vv[1]); st.y = pk2(vv[2], vv[3]);
        *(uint2*)((bf16*)out + (((size_t)b_ * H + h_) * DK + dk) * S + ss) = st;
      } else {
#pragma unroll
        for (int r = 0; r < 4; ++r) {
          const int row = row0 + wm + tm * 16 + quad * 4 + r;
          const float v = (acc[tm][tn][r] + bv) * scale;
          if (MODE == 0) {
            ((float*)out)[(size_t)row * N + col] = v;
          } else {
            const int b_ = row >> 11, s_ = row & (S - 1);
            const int h_ = col >> 6,  dk = col & (DK - 1);
            ((bf16*)out)[(((size_t)b_ * H + h_) * S + s_) * DK + dk] =
                __builtin_bit_cast(bf16, f2bfu(v));
          }
        }
      }
    }
  }
}

// ---------------------------------------------------------------------------
// flash v5 (causal MFMA, in-register softmax). Q,K: [B*H,S,DK] bf16
// (Q pre-scaled by 0.125*log2e); Vt: [B*H,DK,S] bf16.
// Grid (B*H, 8), 512 thr = 8 waves; wave w owns q-rows qbase = q0+w*16+[0,16).
// Swapped QK^T with key permutation kappa(tn,quad,r)=32(tn>>1)+8*quad+4(tn&1)+r:
// lane (quad,lm) holds S[kappa][q=lm] in sc[tn][r]; for PV frag kf the keys
// kf*32+quad*8+j are exactly sc[2kf+(j>>2)][j&3] -> pack in-register, no LDS.
// LDS swizzle f(row)=(row&7)^(((row>>3)&1)<<2) keeps K (permuted rows) and V
// (linear rows) b128 reads at <=8 lanes per 16B column (conflict-free).
// ---------------------------------------------------------------------------
__global__ __launch_bounds__(512)
void flash_mfma(const bf16* __restrict__ Q, const bf16* __restrict__ K,
                const bf16* __restrict__ Vt, bf16* __restrict__ ctx)
{
  __shared__ uint4 KsU[2][512];          // 2 x (64 keys x 64 dk) (16KB)
  __shared__ uint4 VtU[2][512];          // 2 x (64 d x 64 keys)  (16KB)
  __shared__ uint16_t Os[128 * 72];      // epilogue O staging (18KB)

  const int tid  = threadIdx.x;
  const int w    = tid >> 6;             // 0..7
  const int lane = tid & 63;
  const int lm   = lane & 15;
  const int quad = lane >> 4;
  const int bh   = blockIdx.x;           // 0..63
  const int pr   = blockIdx.y;           // 0..7
  const size_t base = (size_t)bh * S * DK;

  const uint4* Kg0 = (const uint4*)(K + base);
  const uint4* Vg0 = (const uint4*)(Vt + (size_t)bh * DK * S);

  // staging: LDS chunk (row r, col c) holds global chunk c ^ f(r),
  // f(r) = (r&7) ^ (((r>>3)&1)<<2); realized via pre-swizzled global source.
  const int rr  = w * 8 + (lane >> 3);                     // staged row
  const int csw = (lane & 7) ^ (lane >> 3) ^ ((w & 1) << 2); // source chunk
  const int fv  = (lm & 7) ^ (((lm >> 3) & 1) << 2);       // f for V rows tn*16+lm
  const int r0  = ((lm >> 2) << 3) | (lm & 3);             // K perm base row

  uint16_t* const Ow = Os + (w * 16) * 72;
  const int b_ = bh >> 4, h_ = bh & (H - 1);

  for (int pass = 0; pass < 2; ++pass) {
    const int qi = pass ? (15 - pr) : pr;
    const int q0 = qi * 128;
    const int qbase = q0 + w * 16;

    bf16x8 qf0, qf1;
    {
      const bf16* qrow = Q + base + (size_t)(qbase + lm) * DK;
      qf0 = __builtin_bit_cast(bf16x8, *(const uint4*)(qrow + quad * 8));
      qf1 = __builtin_bit_cast(bf16x8, *(const uint4*)(qrow + 32 + quad * 8));
    }

    f32x4 o[4] = {};
    float m_i = NEG_BIG, l_i = 0.f;      // stats for q-row lm (lane-local)

    const int nt = 2 * qi + 2;

    // prologue: stage tile 0 into buf 0
    ldst16(&Kg0[(size_t)rr * 8 + csw],       &KsU[0][w * 64]);
    ldst16(&Vg0[(size_t)rr * (S / 8) + csw], &VtU[0][w * 64]);

    int cur = 0;
    for (int t = 0; t < nt; ++t) {
      __syncthreads();
      if (t + 1 < nt) {
        const int k1 = (t + 1) * 64;
        ldst16(&Kg0[(size_t)(k1 + rr) * 8 + csw],         &KsU[cur ^ 1][w * 64]);
        ldst16(&Vg0[(size_t)rr * (S / 8) + k1 / 8 + csw], &VtU[cur ^ 1][w * 64]);
      }
      const int k0 = t * 64;
      if (k0 <= qbase + 15) {            // wave-uniform causal skip
        const uint4* Ks = KsU[cur];
        const uint4* Vs = VtU[cur];

        // swapped QK^T: sc[tn][r] = S[k0 + 32(tn>>1)+8*quad+4(tn&1)+r][qbase+lm]
        f32x4 sc[4];
        __builtin_amdgcn_s_setprio(1);
#pragma unroll
        for (int tn = 0; tn < 4; ++tn) {
          const int row = r0 + ((tn & 1) << 2) + ((tn >> 1) << 5);
          const int fr  = (row & 7) ^ (((row >> 3) & 1) << 2);
          const int cb  = quad ^ fr;
          bf16x8 kb0 = __builtin_bit_cast(bf16x8, Ks[row * 8 + cb]);
          bf16x8 kb1 = __builtin_bit_cast(bf16x8, Ks[row * 8 + (cb ^ 4)]);
          sc[tn] = __builtin_amdgcn_mfma_f32_16x16x32_bf16(
                       kb0, qf0, f32x4{0.f, 0.f, 0.f, 0.f}, 0, 0, 0);
          sc[tn] = __builtin_amdgcn_mfma_f32_16x16x32_bf16(kb1, qf1, sc[tn], 0, 0, 0);
        }
        __builtin_amdgcn_s_setprio(0);

        // causal mask — diagonal tiles only
        if (k0 + 63 > qbase) {
          const int qg = qbase + lm;
#pragma unroll
          for (int tn = 0; tn < 4; ++tn) {
            const int kb_ = k0 + ((tn >> 1) << 5) + (quad << 3) + ((tn & 1) << 2);
#pragma unroll
            for (int r = 0; r < 4; ++r)
              if (kb_ + r > qg) sc[tn][r] = NEG_BIG;
          }
        }

        // per-row stats: lane holds 16 of row lm's keys; reduce across quads
        float mloc = fmaxf(fmaxf(hmax4(sc[0]), hmax4(sc[1])),
                           fmaxf(hmax4(sc[2]), hmax4(sc[3])));
        mloc = fmaxf(mloc, __shfl_xor(mloc, 16));
        mloc = fmaxf(mloc, __shfl_xor(mloc, 32));

        if (__any(mloc > m_i + DEFER_THR)) {   // T13 defer-rescale
          const float mn = fmaxf(m_i, mloc);
          const float al = ex2(m_i - mn);
          l_i *= al; m_i = mn;
          const float a0 = __shfl(al, quad * 4 + 0, 16);
          const float a1 = __shfl(al, quad * 4 + 1, 16);
          const float a2 = __shfl(al, quad * 4 + 2, 16);
          const float a3 = __shfl(al, quad * 4 + 3, 16);
#pragma unroll
          for (int tn = 0; tn < 4; ++tn) {
            o[tn][0] *= a0; o[tn][1] *= a1; o[tn][2] *= a2; o[tn][3] *= a3;
          }
        }

        float ls = 0.f;
#pragma unroll
        for (int tn = 0; tn < 4; ++tn) {
#pragma unroll
          for (int r = 0; r < 4; ++r) sc[tn][r] = ex2(sc[tn][r] - m_i);
          ls += (sc[tn][0] + sc[tn][1]) + (sc[tn][2] + sc[tn][3]);
        }
        l_i += ls;

        // P -> A-frags: pure in-register pack (keys already in frag order)
        uint4 pw0, pw1;
        pw0.x = cvtpk(sc[0][0], sc[0][1]); pw0.y = cvtpk(sc[0][2], sc[0][3]);
        pw0.z = cvtpk(sc[1][0], sc[1][1]); pw0.w = cvtpk(sc[1][2], sc[1][3]);
        pw1.x = cvtpk(sc[2][0], sc[2][1]); pw1.y = cvtpk(sc[2][2], sc[2][3]);
        pw1.z = cvtpk(sc[3][0], sc[3][1]); pw1.w = cvtpk(sc[3][2], sc[3][3]);
        const bf16x8 ap0 = __builtin_bit_cast(bf16x8, pw0);
        const bf16x8 ap1 = __builtin_bit_cast(bf16x8, pw1);

        __builtin_amdgcn_s_setprio(1);
#pragma unroll
        for (int tn = 0; tn < 4; ++tn) {
          const int vrow = tn * 16 + lm;   // d index
          const int cv = quad ^ fv;
          bf16x8 vb0 = __builtin_bit_cast(bf16x8, Vs[vrow * 8 + cv]);
          bf16x8 vb1 = __builtin_bit_cast(bf16x8, Vs[vrow * 8 + (cv ^ 4)]);
          o[tn] = __builtin_amdgcn_mfma_f32_16x16x32_bf16(ap0, vb0, o[tn], 0, 0, 0);
          o[tn] = __builtin_amdgcn_mfma_f32_16x16x32_bf16(ap1, vb1, o[tn], 0, 0, 0);
        }
        __builtin_amdgcn_s_setprio(0);
      }
      cur ^= 1;
    }

    // epilogue: reduce l across quads, normalize, stash O, coalesced store
    __syncthreads();
    {
      float lr = l_i;
      lr += __shfl_xor(lr, 16);
      lr += __shfl_xor(lr, 32);
      const float inv = 1.f / lr;          // for q-row lm
      const float i0 = __shfl(inv, quad * 4 + 0, 16);
      const float i1 = __shfl(inv, quad * 4 + 1, 16);
      const float i2 = __shfl(inv, quad * 4 + 2, 16);
      const float i3 = __shfl(inv, quad * 4 + 3, 16);
#pragma unroll
      for (int tn = 0; tn < 4; ++tn) {
        Ow[(quad * 4 + 0) * 72 + tn * 16 + lm] = f2bfu(o[tn][0] * i0);
        Ow[(quad * 4 + 1) * 72 + tn * 16 + lm] = f2bfu(o[tn][1] * i1);
        Ow[(quad * 4 + 2) * 72 + tn * 16 + lm] = f2bfu(o[tn][2] * i2);
        Ow[(quad * 4 + 3) * 72 + tn * 16 + lm] = f2bfu(o[tn][3] * i3);
      }
    }
    __syncthreads();

#pragma unroll
    for (int i = 0; i < 2; ++i) {
      const int idx = tid + i * 512;       // 0..1023 uint4
      const int row = idx >> 3, c = idx & 7;
      const uint4 v = *(const uint4*)(Os + row * 72 + c * 8);
      *(uint4*)(ctx + ((((size_t)b_ * S + q0 + row) * H + h_) << 6) + c * 8) = v;
    }
  }
}

} // namespace

extern "C" void kernel_launch(void* const* d_in, const int* in_sizes, int n_in,
                              void* d_out, int out_size, void* d_ws, size_t ws_size,
                              hipStream_t stream)
{
  const float* query = (const float*)d_in[0];
  const float* key_  = (const float*)d_in[1];
  const float* value = (const float*)d_in[2];
  const float* Wq    = (const float*)d_in[3];
  const float* bq    = (const float*)d_in[4];
  const float* Wk    = (const float*)d_in[5];
  const float* bk    = (const float*)d_in[6];
  const float* Wv    = (const float*)d_in[7];
  const float* bv    = (const float*)d_in[8];
  const float* Wo    = (const float*)d_in[9];
  const float* bo    = (const float*)d_in[10];
  // d_in[11]: causal mask — applied analytically in flash_mfma.

  const size_t qkv = (size_t)B * H * S * DK; // 8,388,608 elems
  const size_t DD  = (size_t)D * D;          // 1,048,576 elems (2MB bf16)
  bf16* slot0 = (bf16*)d_ws;        // q ; later Wo_bf
  bf16* slot1 = slot0 + qkv;        // k
  bf16* slot2 = slot1 + qkv;        // Wq_bf | Wk_bf ; later vt
  bf16* slot3 = slot2 + qkv;        // vin ; later ctx
  bf16* dout0 = (bf16*)d_out;       // qin ; later Wv_bf   (d_out scratch:
  bf16* dout1 = dout0 + qkv;        // kin                  rewritten at end)

  const int n8in = (int)(qkv / 8);          // 1048576
  const int n8w  = (int)(DD / 8);           // 131072
  const dim3 gproj(D / 128, M / 128);       // (8, 64)
  const dim3 gattn(B * H, 8);               // (64, 8)

  // all three inputs -> bf16 (one launch)
  cvt3<<<dim3(n8in / 256, 3), 256, 0, stream>>>(query, key_, value,
                                                dout0, dout1, slot3, n8in);
  // Wq, Wk -> bf16 (one launch; both parked in slot2, dead until V-gemm)
  cvt3<<<dim3(n8w / 256, 2), 256, 0, stream>>>(Wq, Wk, Wk,
                                               slot2, slot2 + DD, slot2, n8w);
  // Q projection (exp2-domain fold: q = (x@Wq^T + bq) * 0.125 * log2e)
  gemm128<1><<<gproj, 256, 0, stream>>>(dout0, slot2, bq, slot0, D, D, QSCALE);
  // K projection
  gemm128<1><<<gproj, 256, 0, stream>>>(dout1, slot2 + DD, bk, slot1, D, D, 1.0f);
  // Wv -> bf16 (qin region of d_out is dead after Q-gemm)
  cvt3<<<dim3(n8w / 256, 1), 256, 0, stream>>>(Wv, Wv, Wv,
                                               dout0, dout0, dout0, n8w);
  // V projection (transposed output into slot2; Wq/Wk scratch dead)
  gemm128<2><<<gproj, 256, 0, stream>>>(slot3, dout0, bv, slot2, D, D, 1.0f);
  // attention -> ctx (vin dead; ctx overwrites slot3)
  flash_mfma<<<gattn, 512, 0, stream>>>(slot0, slot1, slot2, slot3);
  // Wo -> bf16 (q dead after flash)
  cvt3<<<dim3(n8w / 256, 1), 256, 0, stream>>>(Wo, Wo, Wo,
                                               slot0, slot0, slot0, n8w);
  // output projection (fp32 store)
  gemm128<0><<<gproj, 256, 0, stream>>>(slot3, slot0, bo, d_out, D, D, 1.0f);
}

// Round 4
// 325.816 us; speedup vs baseline: 1.7013x; 1.0540x over previous
//
#include <hip/hip_runtime.h>
#include <hip/hip_bf16.h>
#include <cstdint>
#include <cstddef>

// MultiHeadAttention: B=4,S=2048,D=1024,H=16,DK=64, causal. fp32 in, fp32 out.
// Round 11:
//   proj_qkv: Q/K/V projections batched into ONE dispatch (grid 8x64x3 = 1536
//     blocks), single-buffered 32KB LDS m97 loop, __launch_bounds__(256,3)
//     -> ~3 blocks/CU resident (was 3 sequential launches at 2/CU each).
//     R9 measured dbuf neutral at 2/CU; m114 wave-overlap at 3/CU replaces it.
//   cvtW4: all four weight conversions in one launch (slot4 scratch, guarded
//     by ws_size with full fallback to the R10 sequence).
//   launches: 9 -> 5 on the batched path.
// Carried (verified): flash v5 (in-register softmax, key-permuted swapped
// QK^T, dbuf K/V, T13, exp2-domain); gemm128 dbuf for output projection.
// Fragment layouts (HW-verified): A/B 16x16x32 [m|n=lane&15][k=quad*8+j];
// C/D col=lane&15, row=quad*4+reg.

namespace {

constexpr int B  = 4;
constexpr int S  = 2048;
constexpr int D  = 1024;
constexpr int H  = 16;
constexpr int DK = 64;
constexpr int M  = B * S;
constexpr float LOG2E     = 1.44269504088896f;
constexpr float QSCALE    = 0.125f * LOG2E;  // sm-scale folded with log2(e)
constexpr float NEG_BIG   = -1e30f;
constexpr float DEFER_THR = 8.0f;            // T13, log2 domain (p <= 2^8)

using bf16 = __hip_bfloat16;

typedef __attribute__((ext_vector_type(8))) __bf16 bf16x8;
typedef __attribute__((ext_vector_type(4))) float  f32x4;

__device__ __forceinline__ uint16_t f2bfu(float x) { // RNE fp32->bf16 bits
  uint32_t a = __builtin_bit_cast(uint32_t, x);
  return (uint16_t)((a + 0x7FFFu + ((a >> 16) & 1u)) >> 16);
}
__device__ __forceinline__ uint32_t pk2(float x, float y) {
  return (uint32_t)f2bfu(x) | ((uint32_t)f2bfu(y) << 16);
}
__device__ __forceinline__ float ex2(float x) { // 2^x
  float r; asm("v_exp_f32 %0, %1" : "=v"(r) : "v"(x)); return r;
}
__device__ __forceinline__ uint32_t cvtpk(float lo, float hi) { // {bf16(lo),bf16(hi)}
  uint32_t r;
  asm("v_cvt_pk_bf16_f32 %0, %1, %2" : "=v"(r) : "v"(lo), "v"(hi));
  return r;
}
__device__ __forceinline__ float hmax4(f32x4 v) {
  return fmaxf(fmaxf(v[0], v[1]), fmaxf(v[2], v[3]));
}

// async 16B global -> LDS (wave-uniform LDS base + lane*16 implicit)
__device__ __forceinline__ void ldst16(const uint4* g, uint4* l) {
  __builtin_amdgcn_global_load_lds(
      (const __attribute__((address_space(1))) void*)g,
      (__attribute__((address_space(3))) void*)l, 16, 0, 0);
}

// ---------------------------------------------------------------------------
// fp32 -> bf16 bulk convert, up to 3 tensors per launch (blockIdx.y selects).
// ---------------------------------------------------------------------------
__global__ __launch_bounds__(256)
void cvt3(const float* __restrict__ a, const float* __restrict__ b,
          const float* __restrict__ c, bf16* __restrict__ x,
          bf16* __restrict__ y, bf16* __restrict__ z_, int n8)
{
  const int zz = blockIdx.y;
  const float* src = (zz == 0) ? a : (zz == 1) ? b : c;
  bf16*        dst = (zz == 0) ? x : (zz == 1) ? y : z_;
  const int i = blockIdx.x * 256 + threadIdx.x;
  if (i >= n8) return;
  const float4 p = ((const float4*)src)[2 * i];
  const float4 q = ((const float4*)src)[2 * i + 1];
  uint4 r;
  r.x = pk2(p.x, p.y); r.y = pk2(p.z, p.w);
  r.z = pk2(q.x, q.y); r.w = pk2(q.z, q.w);
  ((uint4*)dst)[i] = r;
}

// fp32 -> bf16, four equal-size tensors into contiguous slabs of dst.
__global__ __launch_bounds__(256)
void cvt4(const float* __restrict__ a, const float* __restrict__ b,
          const float* __restrict__ c, const float* __restrict__ d,
          bf16* __restrict__ dst, int n8)
{
  const int zz = blockIdx.y;
  const float* src = (zz == 0) ? a : (zz == 1) ? b : (zz == 2) ? c : d;
  bf16* out = dst + (size_t)zz * n8 * 8;
  const int i = blockIdx.x * 256 + threadIdx.x;
  if (i >= n8) return;
  const float4 p = ((const float4*)src)[2 * i];
  const float4 q = ((const float4*)src)[2 * i + 1];
  uint4 r;
  r.x = pk2(p.x, p.y); r.y = pk2(p.z, p.w);
  r.z = pk2(q.x, q.y); r.w = pk2(q.z, q.w);
  ((uint4*)out)[i] = r;
}

// ---------------------------------------------------------------------------
// proj_qkv: the three input projections in one dispatch. blockIdx.z picks
// {Q,K,V}. Single-buffer 32KB LDS, 2-barrier m97 loop, 3 blocks/CU.
// z=0: q = (qin@Wq^T+bq)*QSCALE -> [B,H,S,DK]
// z=1: k = (kin@Wk^T+bk)        -> [B,H,S,DK]
// z=2: vt = (vin@Wv^T+bv)       -> [B,H,DK,S]
// ---------------------------------------------------------------------------
__global__ __launch_bounds__(256, 3)
void proj_qkv(const bf16* __restrict__ Aq, const bf16* __restrict__ Ak,
              const bf16* __restrict__ Av, const bf16* __restrict__ Wall,
              const float* __restrict__ bq_, const float* __restrict__ bk_,
              const float* __restrict__ bv_, bf16* __restrict__ qo,
              bf16* __restrict__ ko, bf16* __restrict__ vto)
{
  __shared__ uint4 AsU[1024]; // 128 rows x 8 chunks (16KB)
  __shared__ uint4 BsU[1024];

  const int z = blockIdx.z;
  const bf16*  A    = (z == 0) ? Aq : (z == 1) ? Ak : Av;
  const bf16*  Wb   = Wall + (size_t)z * D * D;
  const float* bias = (z == 0) ? bq_ : (z == 1) ? bk_ : bv_;

  const int tid  = threadIdx.x;
  const int w    = tid >> 6;
  const int lane = tid & 63;
  const int lm   = lane & 15;
  const int quad = lane >> 4;
  const int wm   = (w >> 1) * 64;
  const int wn   = (w & 1) * 64;

  const int row0 = blockIdx.y * 128, col0 = blockIdx.x * 128;
  constexpr int g8 = D >> 3; // 128 uint4 per row

  const uint4* Ag = (const uint4*)A + (size_t)row0 * g8;
  const uint4* Bg = (const uint4*)Wb + (size_t)col0 * g8;

  f32x4 acc[4][4] = {};

  for (int kt = 0; kt < D / 64; ++kt) {
    __syncthreads();
#pragma unroll
    for (int i = 0; i < 4; ++i) {
      const int chunk = i * 256 + w * 64 + lane; // 0..1023
      const int r = chunk >> 3, c = chunk & 7;
      ldst16(&Ag[(size_t)r * g8 + kt * 8 + c], &AsU[i * 256 + w * 64]);
      ldst16(&Bg[(size_t)r * g8 + kt * 8 + c], &BsU[i * 256 + w * 64]);
    }
    __syncthreads();
#pragma unroll
    for (int kk = 0; kk < 2; ++kk) {
      bf16x8 af[4], bfr[4];
#pragma unroll
      for (int tm = 0; tm < 4; ++tm)
        af[tm] = __builtin_bit_cast(bf16x8, AsU[(wm + tm * 16 + lm) * 8 + kk * 4 + quad]);
#pragma unroll
      for (int tn = 0; tn < 4; ++tn)
        bfr[tn] = __builtin_bit_cast(bf16x8, BsU[(wn + tn * 16 + lm) * 8 + kk * 4 + quad]);
#pragma unroll
      for (int tm = 0; tm < 4; ++tm)
#pragma unroll
        for (int tn = 0; tn < 4; ++tn)
          acc[tm][tn] = __builtin_amdgcn_mfma_f32_16x16x32_bf16(af[tm], bfr[tn], acc[tm][tn], 0, 0, 0);
    }
  }

  const float scale = (z == 0) ? QSCALE : 1.0f;
#pragma unroll
  for (int tm = 0; tm < 4; ++tm) {
#pragma unroll
    for (int tn = 0; tn < 4; ++tn) {
      const int col = col0 + wn + tn * 16 + lm;
      const float bv = bias[col];
      if (z == 2) {
        float vv[4];
#pragma unroll
        for (int r = 0; r < 4; ++r) vv[r] = acc[tm][tn][r] + bv;
        const int s0 = row0 + wm + tm * 16 + quad * 4;
        const int b_ = s0 >> 11, ss = s0 & (S - 1);
        const int h_ = col >> 6, dk = col & (DK - 1);
        uint2 st; st.x = pk2(vv[0], vv[1]); st.y = pk2(vv[2], vv[3]);
        *(uint2*)(vto + (((size_t)b_ * H + h_) * DK + dk) * S + ss) = st;
      } else {
        bf16* out = (z == 0) ? qo : ko;
#pragma unroll
        for (int r = 0; r < 4; ++r) {
          const int row = row0 + wm + tm * 16 + quad * 4 + r;
          const float v = (acc[tm][tn][r] + bv) * scale;
          const int b_ = row >> 11, s_ = row & (S - 1);
          const int h_ = col >> 6,  dk = col & (DK - 1);
          out[(((size_t)b_ * H + h_) * S + s_) * DK + dk] =
              __builtin_bit_cast(bf16, f2bfu(v));
        }
      }
    }
  }
}

// ---------------------------------------------------------------------------
// gemm128: out = (A[M,K](bf16) @ Wb[N,K](bf16)^T + bias(fp32)) * scale.
// 128x128 tile, BK=64, dbuf LDS, prefetch after single per-iter barrier.
// MODE 0: fp32 [M,N] store  MODE 1: bf16 [B,H,S,DK]  MODE 2: bf16 [B,H,DK,S]
// (kept for the output projection + ws-small fallback path)
// ---------------------------------------------------------------------------
template <int MODE>
__global__ __launch_bounds__(256)
void gemm128(const bf16* __restrict__ A, const bf16* __restrict__ Wb,
             const float* __restrict__ bias, void* __restrict__ out,
             int N, int K, float scale)
{
  __shared__ uint4 AsU[2][1024]; // 2 x 128 rows x 8 chunks (32KB)
  __shared__ uint4 BsU[2][1024];

  const int tid  = threadIdx.x;
  const int w    = tid >> 6;
  const int lane = tid & 63;
  const int lm   = lane & 15;
  const int quad = lane >> 4;
  const int wm   = (w >> 1) * 64;
  const int wn   = (w & 1) * 64;

  const int row0 = blockIdx.y * 128, col0 = blockIdx.x * 128;
  const int g8 = K >> 3; // uint4 per row

  const uint4* Ag = (const uint4*)A + (size_t)row0 * g8;
  const uint4* Bg = (const uint4*)Wb + (size_t)col0 * g8;

  f32x4 acc[4][4] = {};
  const int KT = K / 64;

  // prologue: stage kt=0 into buf 0
#pragma unroll
  for (int i = 0; i < 4; ++i) {
    const int chunk = i * 256 + w * 64 + lane; // 0..1023
    const int r = chunk >> 3, c = chunk & 7;
    ldst16(&Ag[(size_t)r * g8 + c], &AsU[0][i * 256 + w * 64]);
    ldst16(&Bg[(size_t)r * g8 + c], &BsU[0][i * 256 + w * 64]);
  }

  int cur = 0;
  for (int kt = 0; kt < KT; ++kt) {
    __syncthreads();
    if (kt + 1 < KT) {
#pragma unroll
      for (int i = 0; i < 4; ++i) {
        const int chunk = i * 256 + w * 64 + lane;
        const int r = chunk >> 3, c = chunk & 7;
        ldst16(&Ag[(size_t)r * g8 + (kt + 1) * 8 + c], &AsU[cur ^ 1][i * 256 + w * 64]);
        ldst16(&Bg[(size_t)r * g8 + (kt + 1) * 8 + c], &BsU[cur ^ 1][i * 256 + w * 64]);
      }
    }
#pragma unroll
    for (int kk = 0; kk < 2; ++kk) {
      bf16x8 af[4], bfr[4];
#pragma unroll
      for (int tm = 0; tm < 4; ++tm)
        af[tm] = __builtin_bit_cast(bf16x8, AsU[cur][(wm + tm * 16 + lm) * 8 + kk * 4 + quad]);
#pragma unroll
      for (int tn = 0; tn < 4; ++tn)
        bfr[tn] = __builtin_bit_cast(bf16x8, BsU[cur][(wn + tn * 16 + lm) * 8 + kk * 4 + quad]);
#pragma unroll
      for (int tm = 0; tm < 4; ++tm)
#pragma unroll
        for (int tn = 0; tn < 4; ++tn)
          acc[tm][tn] = __builtin_amdgcn_mfma_f32_16x16x32_bf16(af[tm], bfr[tn], acc[tm][tn], 0, 0, 0);
    }
    cur ^= 1;
  }

#pragma unroll
  for (int tm = 0; tm < 4; ++tm) {
#pragma unroll
    for (int tn = 0; tn < 4; ++tn) {
      const int col = col0 + wn + tn * 16 + lm;
      const float bv = bias[col];
      if (MODE == 2) {
        float vv[4];
#pragma unroll
        for (int r = 0; r < 4; ++r) vv[r] = (acc[tm][tn][r] + bv) * scale;
        const int s0 = row0 + wm + tm * 16 + quad * 4;
        const int b_ = s0 >> 11, ss = s0 & (S - 1);
        const int h_ = col >> 6, dk = col & (DK - 1);
        uint2 st; st.x = pk2(vv[0], vv[1]); st.y = pk2(vv[2], vv[3]);
        *(uint2*)((bf16*)out + (((size_t)b_ * H + h_) * DK + dk) * S + ss) = st;
      } else {
#pragma unroll
        for (int r = 0; r < 4; ++r) {
          const int row = row0 + wm + tm * 16 + quad * 4 + r;
          const float v = (acc[tm][tn][r] + bv) * scale;
          if (MODE == 0) {
            ((float*)out)[(size_t)row * N + col] = v;
          } else {
            const int b_ = row >> 11, s_ = row & (S - 1);
            const int h_ = col >> 6,  dk = col & (DK - 1);
            ((bf16*)out)[(((size_t)b_ * H + h_) * S + s_) * DK + dk] =
                __builtin_bit_cast(bf16, f2bfu(v));
          }
        }
      }
    }
  }
}

// ---------------------------------------------------------------------------
// flash v5 (causal MFMA, in-register softmax). Q,K: [B*H,S,DK] bf16
// (Q pre-scaled by 0.125*log2e); Vt: [B*H,DK,S] bf16.
// Grid (B*H, 8), 512 thr = 8 waves; wave w owns q-rows qbase = q0+w*16+[0,16).
// Swapped QK^T with key permutation kappa(tn,quad,r)=32(tn>>1)+8*quad+4(tn&1)+r:
// lane (quad,lm) holds S[kappa][q=lm] in sc[tn][r]; for PV frag kf the keys
// kf*32+quad*8+j are exactly sc[2kf+(j>>2)][j&3] -> pack in-register, no LDS.
// LDS swizzle f(row)=(row&7)^(((row>>3)&1)<<2) keeps K (permuted rows) and V
// (linear rows) b128 reads at <=8 lanes per 16B column.
// ---------------------------------------------------------------------------
__global__ __launch_bounds__(512)
void flash_mfma(const bf16* __restrict__ Q, const bf16* __restrict__ K,
                const bf16* __restrict__ Vt, bf16* __restrict__ ctx)
{
  __shared__ uint4 KsU[2][512];          // 2 x (64 keys x 64 dk) (16KB)
  __shared__ uint4 VtU[2][512];          // 2 x (64 d x 64 keys)  (16KB)
  __shared__ uint16_t Os[128 * 72];      // epilogue O staging (18KB)

  const int tid  = threadIdx.x;
  const int w    = tid >> 6;             // 0..7
  const int lane = tid & 63;
  const int lm   = lane & 15;
  const int quad = lane >> 4;
  const int bh   = blockIdx.x;           // 0..63
  const int pr   = blockIdx.y;           // 0..7
  const size_t base = (size_t)bh * S * DK;

  const uint4* Kg0 = (const uint4*)(K + base);
  const uint4* Vg0 = (const uint4*)(Vt + (size_t)bh * DK * S);

  // staging: LDS chunk (row r, col c) holds global chunk c ^ f(r),
  // f(r) = (r&7) ^ (((r>>3)&1)<<2); realized via pre-swizzled global source.
  const int rr  = w * 8 + (lane >> 3);                     // staged row
  const int csw = (lane & 7) ^ (lane >> 3) ^ ((w & 1) << 2); // source chunk
  const int fv  = (lm & 7) ^ (((lm >> 3) & 1) << 2);       // f for V rows tn*16+lm
  const int r0  = ((lm >> 2) << 3) | (lm & 3);             // K perm base row

  uint16_t* const Ow = Os + (w * 16) * 72;
  const int b_ = bh >> 4, h_ = bh & (H - 1);

  for (int pass = 0; pass < 2; ++pass) {
    const int qi = pass ? (15 - pr) : pr;
    const int q0 = qi * 128;
    const int qbase = q0 + w * 16;

    bf16x8 qf0, qf1;
    {
      const bf16* qrow = Q + base + (size_t)(qbase + lm) * DK;
      qf0 = __builtin_bit_cast(bf16x8, *(const uint4*)(qrow + quad * 8));
      qf1 = __builtin_bit_cast(bf16x8, *(const uint4*)(qrow + 32 + quad * 8));
    }

    f32x4 o[4] = {};
    float m_i = NEG_BIG, l_i = 0.f;      // stats for q-row lm (lane-local)

    const int nt = 2 * qi + 2;

    // prologue: stage tile 0 into buf 0
    ldst16(&Kg0[(size_t)rr * 8 + csw],       &KsU[0][w * 64]);
    ldst16(&Vg0[(size_t)rr * (S / 8) + csw], &VtU[0][w * 64]);

    int cur = 0;
    for (int t = 0; t < nt; ++t) {
      __syncthreads();
      if (t + 1 < nt) {
        const int k1 = (t + 1) * 64;
        ldst16(&Kg0[(size_t)(k1 + rr) * 8 + csw],         &KsU[cur ^ 1][w * 64]);
        ldst16(&Vg0[(size_t)rr * (S / 8) + k1 / 8 + csw], &VtU[cur ^ 1][w * 64]);
      }
      const int k0 = t * 64;
      if (k0 <= qbase + 15) {            // wave-uniform causal skip
        const uint4* Ks = KsU[cur];
        const uint4* Vs = VtU[cur];

        // swapped QK^T: sc[tn][r] = S[k0 + 32(tn>>1)+8*quad+4(tn&1)+r][qbase+lm]
        f32x4 sc[4];
        __builtin_amdgcn_s_setprio(1);
#pragma unroll
        for (int tn = 0; tn < 4; ++tn) {
          const int row = r0 + ((tn & 1) << 2) + ((tn >> 1) << 5);
          const int fr  = (row & 7) ^ (((row >> 3) & 1) << 2);
          const int cb  = quad ^ fr;
          bf16x8 kb0 = __builtin_bit_cast(bf16x8, Ks[row * 8 + cb]);
          bf16x8 kb1 = __builtin_bit_cast(bf16x8, Ks[row * 8 + (cb ^ 4)]);
          sc[tn] = __builtin_amdgcn_mfma_f32_16x16x32_bf16(
                       kb0, qf0, f32x4{0.f, 0.f, 0.f, 0.f}, 0, 0, 0);
          sc[tn] = __builtin_amdgcn_mfma_f32_16x16x32_bf16(kb1, qf1, sc[tn], 0, 0, 0);
        }
        __builtin_amdgcn_s_setprio(0);

        // causal mask — diagonal tiles only
        if (k0 + 63 > qbase) {
          const int qg = qbase + lm;
#pragma unroll
          for (int tn = 0; tn < 4; ++tn) {
            const int kb_ = k0 + ((tn >> 1) << 5) + (quad << 3) + ((tn & 1) << 2);
#pragma unroll
            for (int r = 0; r < 4; ++r)
              if (kb_ + r > qg) sc[tn][r] = NEG_BIG;
          }
        }

        // per-row stats: lane holds 16 of row lm's keys; reduce across quads
        float mloc = fmaxf(fmaxf(hmax4(sc[0]), hmax4(sc[1])),
                           fmaxf(hmax4(sc[2]), hmax4(sc[3])));
        mloc = fmaxf(mloc, __shfl_xor(mloc, 16));
        mloc = fmaxf(mloc, __shfl_xor(mloc, 32));

        if (__any(mloc > m_i + DEFER_THR)) {   // T13 defer-rescale
          const float mn = fmaxf(m_i, mloc);
          const float al = ex2(m_i - mn);
          l_i *= al; m_i = mn;
          const float a0 = __shfl(al, quad * 4 + 0, 16);
          const float a1 = __shfl(al, quad * 4 + 1, 16);
          const float a2 = __shfl(al, quad * 4 + 2, 16);
          const float a3 = __shfl(al, quad * 4 + 3, 16);
#pragma unroll
          for (int tn = 0; tn < 4; ++tn) {
            o[tn][0] *= a0; o[tn][1] *= a1; o[tn][2] *= a2; o[tn][3] *= a3;
          }
        }

        float ls = 0.f;
#pragma unroll
        for (int tn = 0; tn < 4; ++tn) {
#pragma unroll
          for (int r = 0; r < 4; ++r) sc[tn][r] = ex2(sc[tn][r] - m_i);
          ls += (sc[tn][0] + sc[tn][1]) + (sc[tn][2] + sc[tn][3]);
        }
        l_i += ls;

        // P -> A-frags: pure in-register pack (keys already in frag order)
        uint4 pw0, pw1;
        pw0.x = cvtpk(sc[0][0], sc[0][1]); pw0.y = cvtpk(sc[0][2], sc[0][3]);
        pw0.z = cvtpk(sc[1][0], sc[1][1]); pw0.w = cvtpk(sc[1][2], sc[1][3]);
        pw1.x = cvtpk(sc[2][0], sc[2][1]); pw1.y = cvtpk(sc[2][2], sc[2][3]);
        pw1.z = cvtpk(sc[3][0], sc[3][1]); pw1.w = cvtpk(sc[3][2], sc[3][3]);
        const bf16x8 ap0 = __builtin_bit_cast(bf16x8, pw0);
        const bf16x8 ap1 = __builtin_bit_cast(bf16x8, pw1);

        __builtin_amdgcn_s_setprio(1);
#pragma unroll
        for (int tn = 0; tn < 4; ++tn) {
          const int vrow = tn * 16 + lm;   // d index
          const int cv = quad ^ fv;
          bf16x8 vb0 = __builtin_bit_cast(bf16x8, Vs[vrow * 8 + cv]);
          bf16x8 vb1 = __builtin_bit_cast(bf16x8, Vs[vrow * 8 + (cv ^ 4)]);
          o[tn] = __builtin_amdgcn_mfma_f32_16x16x32_bf16(ap0, vb0, o[tn], 0, 0, 0);
          o[tn] = __builtin_amdgcn_mfma_f32_16x16x32_bf16(ap1, vb1, o[tn], 0, 0, 0);
        }
        __builtin_amdgcn_s_setprio(0);
      }
      cur ^= 1;
    }

    // epilogue: reduce l across quads, normalize, stash O, coalesced store
    __syncthreads();
    {
      float lr = l_i;
      lr += __shfl_xor(lr, 16);
      lr += __shfl_xor(lr, 32);
      const float inv = 1.f / lr;          // for q-row lm
      const float i0 = __shfl(inv, quad * 4 + 0, 16);
      const float i1 = __shfl(inv, quad * 4 + 1, 16);
      const float i2 = __shfl(inv, quad * 4 + 2, 16);
      const float i3 = __shfl(inv, quad * 4 + 3, 16);
#pragma unroll
      for (int tn = 0; tn < 4; ++tn) {
        Ow[(quad * 4 + 0) * 72 + tn * 16 + lm] = f2bfu(o[tn][0] * i0);
        Ow[(quad * 4 + 1) * 72 + tn * 16 + lm] = f2bfu(o[tn][1] * i1);
        Ow[(quad * 4 + 2) * 72 + tn * 16 + lm] = f2bfu(o[tn][2] * i2);
        Ow[(quad * 4 + 3) * 72 + tn * 16 + lm] = f2bfu(o[tn][3] * i3);
      }
    }
    __syncthreads();

#pragma unroll
    for (int i = 0; i < 2; ++i) {
      const int idx = tid + i * 512;       // 0..1023 uint4
      const int row = idx >> 3, c = idx & 7;
      const uint4 v = *(const uint4*)(Os + row * 72 + c * 8);
      *(uint4*)(ctx + ((((size_t)b_ * S + q0 + row) * H + h_) << 6) + c * 8) = v;
    }
  }
}

} // namespace

extern "C" void kernel_launch(void* const* d_in, const int* in_sizes, int n_in,
                              void* d_out, int out_size, void* d_ws, size_t ws_size,
                              hipStream_t stream)
{
  const float* query = (const float*)d_in[0];
  const float* key_  = (const float*)d_in[1];
  const float* value = (const float*)d_in[2];
  const float* Wq    = (const float*)d_in[3];
  const float* bq    = (const float*)d_in[4];
  const float* Wk    = (const float*)d_in[5];
  const float* bk    = (const float*)d_in[6];
  const float* Wv    = (const float*)d_in[7];
  const float* bv    = (const float*)d_in[8];
  const float* Wo    = (const float*)d_in[9];
  const float* bo    = (const float*)d_in[10];
  // d_in[11]: causal mask — applied analytically in flash_mfma.

  const size_t qkv = (size_t)B * H * S * DK; // 8,388,608 elems (16.8MB bf16)
  const size_t DD  = (size_t)D * D;          // 1,048,576 elems (2MB bf16)
  bf16* slot0 = (bf16*)d_ws;        // q
  bf16* slot1 = slot0 + qkv;        // k
  bf16* slot2 = slot1 + qkv;        // vt (batched) / W scratch (fallback)
  bf16* slot3 = slot2 + qkv;        // vin ; later ctx
  bf16* slot4 = slot3 + qkv;        // batched only: Wq|Wk|Wv|Wo bf16 (8MB)
  bf16* dout0 = (bf16*)d_out;       // qin          (d_out scratch: fully
  bf16* dout1 = dout0 + qkv;        // kin           rewritten at the end)

  const int n8in = (int)(qkv / 8);          // 1048576
  const int n8w  = (int)(DD / 8);           // 131072
  const dim3 gproj(D / 128, M / 128);       // (8, 64)
  const dim3 gattn(B * H, 8);               // (64, 8)

  const size_t need = (4 * qkv + 4 * DD) * sizeof(bf16); // 75,497,472 B

  if (ws_size >= need) {
    // ---- batched path (5 launches) ----
    cvt3<<<dim3(n8in / 256, 3), 256, 0, stream>>>(query, key_, value,
                                                  dout0, dout1, slot3, n8in);
    cvt4<<<dim3(n8w / 256, 4), 256, 0, stream>>>(Wq, Wk, Wv, Wo, slot4, n8w);
    proj_qkv<<<dim3(D / 128, M / 128, 3), 256, 0, stream>>>(
        dout0, dout1, slot3, slot4, bq, bk, bv, slot0, slot1, slot2);
    flash_mfma<<<gattn, 512, 0, stream>>>(slot0, slot1, slot2, slot3);
    gemm128<0><<<gproj, 256, 0, stream>>>(slot3, slot4 + 3 * DD, bo, d_out,
                                          D, D, 1.0f);
  } else {
    // ---- fallback: R10 sequence (9 launches) ----
    cvt3<<<dim3(n8in / 256, 3), 256, 0, stream>>>(query, key_, value,
                                                  dout0, dout1, slot3, n8in);
    cvt3<<<dim3(n8w / 256, 2), 256, 0, stream>>>(Wq, Wk, Wk,
                                                 slot2, slot2 + DD, slot2, n8w);
    gemm128<1><<<gproj, 256, 0, stream>>>(dout0, slot2, bq, slot0, D, D, QSCALE);
    gemm128<1><<<gproj, 256, 0, stream>>>(dout1, slot2 + DD, bk, slot1, D, D, 1.0f);
    cvt3<<<dim3(n8w / 256, 1), 256, 0, stream>>>(Wv, Wv, Wv,
                                                 dout0, dout0, dout0, n8w);
    gemm128<2><<<gproj, 256, 0, stream>>>(slot3, dout0, bv, slot2, D, D, 1.0f);
    flash_mfma<<<gattn, 512, 0, stream>>>(slot0, slot1, slot2, slot3);
    cvt3<<<dim3(n8w / 256, 1), 256, 0, stream>>>(Wo, Wo, Wo,
                                                 slot0, slot0, slot0, n8w);
    gemm128<0><<<gproj, 256, 0, stream>>>(slot3, slot0, bo, d_out, D, D, 1.0f);
  }
}